// Round 4
// baseline (5406.421 us; speedup 1.0000x reference)
//
#include <hip/hip_runtime.h>
#include <math.h>

#define N_NODES 100000
#define DIM 128
#define NREL 4
#define NEDGE 1600000
#define LN_EPS 1e-3f

__device__ __forceinline__ float bf2f(unsigned short b) {
    return __uint_as_float(((unsigned int)b) << 16);
}
__device__ __forceinline__ unsigned short f2bf(float f) {
    unsigned int u = __float_as_uint(f);
    u += 0x7FFFu + ((u >> 16) & 1u);      // RN-even
    return (unsigned short)(u >> 16);
}

// ---------------------------------------------------------------------------
// Prep: bfr[r][d] = b_fuse[d] + sum_k rel[r][k]*W_fuse[D+k][d]; softmax(rel_w)
// ---------------------------------------------------------------------------
__global__ __launch_bounds__(512) void prep_kernel(
    const float* __restrict__ rel_emb, const float* __restrict__ W_fuse,
    const float* __restrict__ b_fuse, const float* __restrict__ rel_weights,
    float* __restrict__ bfr, float* __restrict__ wsm)
{
    int t = threadIdx.x;
    int r = t >> 7;
    int d = t & 127;
    float acc = b_fuse[d];
    for (int k = 0; k < DIM; ++k)
        acc += rel_emb[r * DIM + k] * W_fuse[(DIM + k) * DIM + d];
    bfr[r * DIM + d] = acc;
    if (t < NREL) {
        float m = rel_weights[0];
        for (int i = 1; i < NREL; ++i) m = fmaxf(m, rel_weights[i]);
        float s = 0.f;
        for (int i = 0; i < NREL; ++i) s += expf(rel_weights[i] - m);
        wsm[t] = expf(rel_weights[t] - m) / s;
    }
}

// ---------------------------------------------------------------------------
// X (fp32) -> Xb (bf16)
// ---------------------------------------------------------------------------
__global__ __launch_bounds__(256) void xb_kernel(
    const float* __restrict__ X, unsigned short* __restrict__ Xb)
{
    int idx = blockIdx.x * 256 + threadIdx.x;   // N*DIM/4 exact
    float4 f = ((const float4*)X)[idx];
    ushort4 o;
    o.x = f2bf(f.x); o.y = f2bf(f.y); o.z = f2bf(f.z); o.w = f2bf(f.w);
    ((ushort4*)Xb)[idx] = o;
}

// ---------------------------------------------------------------------------
// CSR build (grid.y = relation within group of 2)
// ---------------------------------------------------------------------------
__global__ __launch_bounds__(256) void hist_kernel(
    const int* __restrict__ arows, int r0, int* __restrict__ counts)
{
    int e = blockIdx.x * 256 + threadIdx.x;
    int rl = blockIdx.y;
    if (e < NEDGE) {
        int row = arows[(size_t)(r0 + rl) * NEDGE + e];
        atomicAdd(&counts[rl * N_NODES + row], 1);
    }
}

// in-place per-chunk exclusive scan (1024 elems/block)
__global__ __launch_bounds__(256) void scan1_kernel(
    int* __restrict__ counts, int* __restrict__ chunksums, int M)
{
    __shared__ int s[256];
    int chunk = blockIdx.x, t = threadIdx.x;
    int base = chunk * 1024 + t * 4;
    int v0 = (base + 0 < M) ? counts[base + 0] : 0;
    int v1 = (base + 1 < M) ? counts[base + 1] : 0;
    int v2 = (base + 2 < M) ? counts[base + 2] : 0;
    int v3 = (base + 3 < M) ? counts[base + 3] : 0;
    int p1 = v0, p2 = v0 + v1, p3 = v0 + v1 + v2, tsum = p3 + v3;
    int run = tsum;
    s[t] = run;
    __syncthreads();
    for (int off = 1; off < 256; off <<= 1) {
        int other = (t >= off) ? s[t - off] : 0;
        __syncthreads();
        run += other;
        s[t] = run;
        __syncthreads();
    }
    int excl = run - tsum;
    if (t == 255) chunksums[chunk] = run;
    if (base + 0 < M) counts[base + 0] = excl;
    if (base + 1 < M) counts[base + 1] = excl + p1;
    if (base + 2 < M) counts[base + 2] = excl + p2;
    if (base + 3 < M) counts[base + 3] = excl + p3;
}

// exclusive scan of chunk sums (<=512) in place
__global__ __launch_bounds__(512) void scan2_kernel(
    int* __restrict__ chunksums, int nchunks)
{
    __shared__ int s[512];
    int t = threadIdx.x;
    int v = (t < nchunks) ? chunksums[t] : 0;
    int run = v;
    s[t] = run;
    __syncthreads();
    for (int off = 1; off < 512; off <<= 1) {
        int other = (t >= off) ? s[t - off] : 0;
        __syncthreads();
        run += other;
        s[t] = run;
        __syncthreads();
    }
    if (t < nchunks) chunksums[t] = run - v;
}

// bucket edges by row; edge = int2(col<<5 | dest_local, val_fp32).
// counts (within-chunk excl starts) mutate into within-chunk ENDs;
// global position = counts-bump + chunks[g>>10]  (scan3 folded in here).
__global__ __launch_bounds__(256) void reorder_kernel(
    const int* __restrict__ arows, const int* __restrict__ acols,
    const float* __restrict__ avals, int r0,
    int* __restrict__ counts, const int* __restrict__ chunks,
    int2* __restrict__ edges)
{
    int e = blockIdx.x * 256 + threadIdx.x;
    int rl = blockIdx.y;
    if (e < NEDGE) {
        size_t off = (size_t)(r0 + rl) * NEDGE + e;
        int row = arows[off];
        int g = rl * N_NODES + row;
        int pos = atomicAdd(&counts[g], 1) + chunks[g >> 10];
        edges[pos] = make_int2((acols[off] << 5) | (row & 31),
                               __float_as_int(avals[off]));
    }
}

// ---------------------------------------------------------------------------
// Mega kernel: per 32-row tile, per relation in group:
//   edge-parallel gather (wave-per-edge, ds_add_f32 into LDS) ->
//   GEMM1(relu) -> GEMM2, comb accumulated in registers.
// Last group fuses gate GEMM + residual + LayerNorm epilogue.
// Waves: w owns rows [8w,8w+8) in GEMM phases; lane l owns cols l, l+64.
// ---------------------------------------------------------------------------
__global__ __launch_bounds__(256) void mega_kernel(
    const unsigned short* __restrict__ Xb,
    const float* __restrict__ X,
    const int* __restrict__ counts,     // within-chunk end offsets
    const int* __restrict__ chunks,     // chunk base offsets
    const int2* __restrict__ edges,
    const float* __restrict__ W1,
    const float* __restrict__ bfr,
    const float* __restrict__ Wr,
    const float* __restrict__ br,
    const float* __restrict__ wsm,
    int r0, int nr, int accumulate, int do_final,
    const float* __restrict__ Wg,
    const float* __restrict__ bg,
    const float* __restrict__ gamma,
    const float* __restrict__ beta,
    float* __restrict__ comb,           // aliases out
    float* __restrict__ out)
{
    __shared__ float sIn[32][DIM];
    __shared__ float red[32][8], red2[32][8];
    __shared__ float smu[32], srs[32];

    int t = threadIdx.x;
    int row0 = blockIdx.x * 32;
    int w = t >> 6;            // wave 0..3
    int l = t & 63;

    float comb_acc[8][2];
#pragma unroll
    for (int rr = 0; rr < 8; ++rr) {
        if (accumulate) {
            size_t gi = (size_t)(row0 + w * 8 + rr) * DIM + l;
            comb_acc[rr][0] = comb[gi];
            comb_acc[rr][1] = comb[gi + 64];
        } else {
            comb_acc[rr][0] = 0.f;
            comb_acc[rr][1] = 0.f;
        }
    }

    for (int rl = 0; rl < nr; ++rl) {
        int r = r0 + rl;
        __syncthreads();   // sIn free (prev GEMM2 reads done / init)

        // zero the accumulation tile
        {
            float4 z = make_float4(0.f, 0.f, 0.f, 0.f);
            float4* sz = (float4*)&sIn[0][0];
            for (int i = t; i < 32 * DIM / 4; i += 256) sz[i] = z;
        }
        __syncthreads();

        // ---- Phase A: edge-parallel gather, wave-per-edge, LDS atomics
        {
            int gbase = rl * N_NODES + row0;
            int s = (gbase == 0) ? 0
                    : counts[gbase - 1] + chunks[(gbase - 1) >> 10];
            int e = counts[gbase + 31] + chunks[(gbase + 31) >> 10];
            int cnt = e - s;
            int per = (cnt + 3) >> 2;
            int wb = s + w * per;
            int we = wb + per;
            if (we > e) we = e;
            wb = __builtin_amdgcn_readfirstlane(wb);
            we = __builtin_amdgcn_readfirstlane(we);

            int ee = wb;
            for (; ee + 4 <= we; ee += 4) {
                int2 e0 = edges[ee + 0];
                int2 e1 = edges[ee + 1];
                int2 e2 = edges[ee + 2];
                int2 e3 = edges[ee + 3];
                const unsigned short* x0 = Xb + ((size_t)((unsigned)e0.x >> 5) << 7);
                const unsigned short* x1 = Xb + ((size_t)((unsigned)e1.x >> 5) << 7);
                const unsigned short* x2 = Xb + ((size_t)((unsigned)e2.x >> 5) << 7);
                const unsigned short* x3 = Xb + ((size_t)((unsigned)e3.x >> 5) << 7);
                unsigned short a0 = x0[l], b0 = x0[l + 64];
                unsigned short a1 = x1[l], b1 = x1[l + 64];
                unsigned short a2 = x2[l], b2 = x2[l + 64];
                unsigned short a3 = x3[l], b3 = x3[l + 64];
                float v0 = __int_as_float(e0.y);
                float v1 = __int_as_float(e1.y);
                float v2 = __int_as_float(e2.y);
                float v3 = __int_as_float(e3.y);
                int d0 = e0.x & 31, d1 = e1.x & 31;
                int d2 = e2.x & 31, d3 = e3.x & 31;
                atomicAdd(&sIn[d0][l],      v0 * bf2f(a0));
                atomicAdd(&sIn[d0][l + 64], v0 * bf2f(b0));
                atomicAdd(&sIn[d1][l],      v1 * bf2f(a1));
                atomicAdd(&sIn[d1][l + 64], v1 * bf2f(b1));
                atomicAdd(&sIn[d2][l],      v2 * bf2f(a2));
                atomicAdd(&sIn[d2][l + 64], v2 * bf2f(b2));
                atomicAdd(&sIn[d3][l],      v3 * bf2f(a3));
                atomicAdd(&sIn[d3][l + 64], v3 * bf2f(b3));
            }
            for (; ee < we; ++ee) {
                int2 e0 = edges[ee];
                const unsigned short* x0 = Xb + ((size_t)((unsigned)e0.x >> 5) << 7);
                unsigned short a0 = x0[l], b0 = x0[l + 64];
                float v0 = __int_as_float(e0.y);
                int d0 = e0.x & 31;
                atomicAdd(&sIn[d0][l],      v0 * bf2f(a0));
                atomicAdd(&sIn[d0][l + 64], v0 * bf2f(b0));
            }
        }
        __syncthreads();

        // ---- Phase B: GEMM1 (msg @ W1), relu + bfr, back into sIn
        float acc1[8][2];
#pragma unroll
        for (int rr = 0; rr < 8; ++rr) { acc1[rr][0] = 0.f; acc1[rr][1] = 0.f; }
        for (int k4 = 0; k4 < DIM / 4; ++k4) {
            float wa[4], wb4[4];
#pragma unroll
            for (int j = 0; j < 4; ++j) {
                wa[j]  = W1[(k4 * 4 + j) * DIM + l];
                wb4[j] = W1[(k4 * 4 + j) * DIM + l + 64];
            }
#pragma unroll
            for (int rr = 0; rr < 8; ++rr) {
                float4 m = *(const float4*)&sIn[w * 8 + rr][k4 * 4];
                acc1[rr][0] += m.x * wa[0]  + m.y * wa[1]  + m.z * wa[2]  + m.w * wa[3];
                acc1[rr][1] += m.x * wb4[0] + m.y * wb4[1] + m.z * wb4[2] + m.w * wb4[3];
            }
        }
        __syncthreads();
        {
            float b0 = bfr[r * DIM + l], b1 = bfr[r * DIM + l + 64];
#pragma unroll
            for (int rr = 0; rr < 8; ++rr) {
                sIn[w * 8 + rr][l]      = fmaxf(acc1[rr][0] + b0, 0.f);
                sIn[w * 8 + rr][l + 64] = fmaxf(acc1[rr][1] + b1, 0.f);
            }
        }
        __syncthreads();

        // ---- Phase C: GEMM2 (@ W_rel[r]), weighted accumulate in regs
        const float* W2 = Wr + (size_t)r * DIM * DIM;
        float acc2[8][2];
#pragma unroll
        for (int rr = 0; rr < 8; ++rr) { acc2[rr][0] = 0.f; acc2[rr][1] = 0.f; }
        for (int k4 = 0; k4 < DIM / 4; ++k4) {
            float wa[4], wb4[4];
#pragma unroll
            for (int j = 0; j < 4; ++j) {
                wa[j]  = W2[(k4 * 4 + j) * DIM + l];
                wb4[j] = W2[(k4 * 4 + j) * DIM + l + 64];
            }
#pragma unroll
            for (int rr = 0; rr < 8; ++rr) {
                float4 m = *(const float4*)&sIn[w * 8 + rr][k4 * 4];
                acc2[rr][0] += m.x * wa[0]  + m.y * wa[1]  + m.z * wa[2]  + m.w * wa[3];
                acc2[rr][1] += m.x * wb4[0] + m.y * wb4[1] + m.z * wb4[2] + m.w * wb4[3];
            }
        }
        {
            float wr_ = wsm[r];
            float bb0 = br[r * DIM + l], bb1 = br[r * DIM + l + 64];
#pragma unroll
            for (int rr = 0; rr < 8; ++rr) {
                comb_acc[rr][0] += wr_ * (acc2[rr][0] + bb0);
                comb_acc[rr][1] += wr_ * (acc2[rr][1] + bb1);
            }
        }
    }

    if (!do_final) {
#pragma unroll
        for (int rr = 0; rr < 8; ++rr) {
            size_t gi = (size_t)(row0 + w * 8 + rr) * DIM + l;
            comb[gi]      = comb_acc[rr][0];
            comb[gi + 64] = comb_acc[rr][1];
        }
        return;
    }

    // ---- Final: out = LN(X + sigmoid(X@Wg + bg) * comb)
    __syncthreads();
    {
        const float4* src = (const float4*)(X + (size_t)row0 * DIM);
        float4* dst = (float4*)&sIn[0][0];
        for (int i = t; i < 32 * DIM / 4; i += 256) dst[i] = src[i];
    }
    __syncthreads();

    float accg[8][2];
#pragma unroll
    for (int rr = 0; rr < 8; ++rr) { accg[rr][0] = 0.f; accg[rr][1] = 0.f; }
    for (int k4 = 0; k4 < DIM / 4; ++k4) {
        float wa[4], wb4[4];
#pragma unroll
        for (int j = 0; j < 4; ++j) {
            wa[j]  = Wg[(k4 * 4 + j) * DIM + l];
            wb4[j] = Wg[(k4 * 4 + j) * DIM + l + 64];
        }
#pragma unroll
        for (int rr = 0; rr < 8; ++rr) {
            float4 m = *(const float4*)&sIn[w * 8 + rr][k4 * 4];
            accg[rr][0] += m.x * wa[0]  + m.y * wa[1]  + m.z * wa[2]  + m.w * wa[3];
            accg[rr][1] += m.x * wb4[0] + m.y * wb4[1] + m.z * wb4[2] + m.w * wb4[3];
        }
    }
    float xv[8][2];
    {
        float bg0 = bg[l], bg1 = bg[l + 64];
#pragma unroll
        for (int rr = 0; rr < 8; ++rr) {
            int row = w * 8 + rr;
            float g0 = 1.f / (1.f + expf(-(accg[rr][0] + bg0)));
            float g1 = 1.f / (1.f + expf(-(accg[rr][1] + bg1)));
            xv[rr][0] = sIn[row][l]      + g0 * comb_acc[rr][0];
            xv[rr][1] = sIn[row][l + 64] + g1 * comb_acc[rr][1];
        }
    }
    __syncthreads();
#pragma unroll
    for (int rr = 0; rr < 8; ++rr) {
        sIn[w * 8 + rr][l]      = xv[rr][0];
        sIn[w * 8 + rr][l + 64] = xv[rr][1];
    }
    __syncthreads();

    {
        int row = t >> 3, seg = t & 7;
        float s = 0.f, s2 = 0.f;
#pragma unroll
        for (int i = 0; i < 16; ++i) {
            float v = sIn[row][seg * 16 + i];
            s += v; s2 += v * v;
        }
        red[row][seg] = s;
        red2[row][seg] = s2;
    }
    __syncthreads();
    if ((t & 7) == 0) {
        int row = t >> 3;
        float ts = 0.f, ts2 = 0.f;
#pragma unroll
        for (int i = 0; i < 8; ++i) { ts += red[row][i]; ts2 += red2[row][i]; }
        float mu = ts / DIM;
        float var = ts2 / DIM - mu * mu;
        smu[row] = mu;
        srs[row] = rsqrtf(var + LN_EPS);
    }
    __syncthreads();
    {
        float gm0 = gamma[l], gm1 = gamma[l + 64];
        float bt0 = beta[l],  bt1 = beta[l + 64];
#pragma unroll
        for (int rr = 0; rr < 8; ++rr) {
            int row = w * 8 + rr;
            size_t gi = (size_t)(row0 + row) * DIM + l;
            out[gi]      = (sIn[row][l]      - smu[row]) * srs[row] * gm0 + bt0;
            out[gi + 64] = (sIn[row][l + 64] - smu[row]) * srs[row] * gm1 + bt1;
        }
    }
}

// ---------------------------------------------------------------------------
extern "C" void kernel_launch(void* const* d_in, const int* in_sizes, int n_in,
                              void* d_out, int out_size, void* d_ws, size_t ws_size,
                              hipStream_t stream) {
    const float* X     = (const float*)d_in[0];
    const float* rel   = (const float*)d_in[1];
    const int*   arows = (const int*)d_in[2];
    const int*   acols = (const int*)d_in[3];
    const float* avals = (const float*)d_in[4];
    const float* Wf    = (const float*)d_in[5];
    const float* bf    = (const float*)d_in[6];
    const float* Wr    = (const float*)d_in[7];
    const float* br    = (const float*)d_in[8];
    const float* rw    = (const float*)d_in[9];
    const float* Wg    = (const float*)d_in[10];
    const float* bg    = (const float*)d_in[11];
    const float* gamma = (const float*)d_in[12];
    const float* beta  = (const float*)d_in[13];
    float* out = (float*)d_out;

    // groups of 2 relations:
    // Xb 25.6MB + edges 2*E*8 = 25.6MB + counts 0.8MB + small  ~= 52.06MB
    const size_t XB_B = (size_t)N_NODES * DIM * 2;
    unsigned short* Xb     = (unsigned short*)d_ws;
    int2*           edges  = (int2*)((char*)d_ws + XB_B);
    int*            counts = (int*)(edges + 2 * (size_t)NEDGE);
    int*            chunks = counts + 2 * N_NODES;
    float*          bfr    = (float*)(chunks + 512);
    float*          wsm    = bfr + NREL * DIM;
    float*          comb   = out;   // accumulated in d_out; final in-place

    prep_kernel<<<1, 512, 0, stream>>>(rel, Wf, bf, rw, bfr, wsm);
    xb_kernel<<<N_NODES * DIM / 4 / 256, 256, 0, stream>>>(X, Xb);

    const int EB = (NEDGE + 255) / 256;        // 6250
    const int M = 2 * N_NODES;                 // 200000
    const int nch = (M + 1023) / 1024;         // 196
    for (int r0 = 0; r0 < NREL; r0 += 2) {
        hipMemsetAsync(counts, 0, (size_t)M * sizeof(int), stream);
        hist_kernel<<<dim3(EB, 2), 256, 0, stream>>>(arows, r0, counts);
        scan1_kernel<<<nch, 256, 0, stream>>>(counts, chunks, M);
        scan2_kernel<<<1, 512, 0, stream>>>(chunks, nch);
        reorder_kernel<<<dim3(EB, 2), 256, 0, stream>>>(
            arows, acols, avals, r0, counts, chunks, edges);
        mega_kernel<<<N_NODES / 32, 256, 0, stream>>>(
            Xb, X, counts, chunks, edges, Wf, bfr, Wr, br, wsm,
            r0, 2, r0 > 0 ? 1 : 0, (r0 + 2 == NREL) ? 1 : 0,
            Wg, bg, gamma, beta, comb, out);
    }
}

// Round 5
// 1743.851 us; speedup vs baseline: 3.1003x; 3.1003x over previous
//
#include <hip/hip_runtime.h>
#include <math.h>

#define N_NODES 100000
#define DIM 128
#define NREL 4
#define NEDGE 1600000
#define LN_EPS 1e-3f

__device__ __forceinline__ float bf2f(unsigned short b) {
    return __uint_as_float(((unsigned int)b) << 16);
}
__device__ __forceinline__ unsigned short f2bf(float f) {
    unsigned int u = __float_as_uint(f);
    u += 0x7FFFu + ((u >> 16) & 1u);      // RN-even
    return (unsigned short)(u >> 16);
}

// ---------------------------------------------------------------------------
// Prep: bfr[r][d] = b_fuse[d] + sum_k rel[r][k]*W_fuse[D+k][d]; softmax(rel_w)
// ---------------------------------------------------------------------------
__global__ __launch_bounds__(512) void prep_kernel(
    const float* __restrict__ rel_emb, const float* __restrict__ W_fuse,
    const float* __restrict__ b_fuse, const float* __restrict__ rel_weights,
    float* __restrict__ bfr, float* __restrict__ wsm)
{
    int t = threadIdx.x;
    int r = t >> 7;
    int d = t & 127;
    float acc = b_fuse[d];
    for (int k = 0; k < DIM; ++k)
        acc += rel_emb[r * DIM + k] * W_fuse[(DIM + k) * DIM + d];
    bfr[r * DIM + d] = acc;
    if (t < NREL) {
        float m = rel_weights[0];
        for (int i = 1; i < NREL; ++i) m = fmaxf(m, rel_weights[i]);
        float s = 0.f;
        for (int i = 0; i < NREL; ++i) s += expf(rel_weights[i] - m);
        wsm[t] = expf(rel_weights[t] - m) / s;
    }
}

// ---------------------------------------------------------------------------
// X (fp32) -> Xb (bf16)
// ---------------------------------------------------------------------------
__global__ __launch_bounds__(256) void xb_kernel(
    const float* __restrict__ X, unsigned short* __restrict__ Xb)
{
    int idx = blockIdx.x * 256 + threadIdx.x;   // N*DIM/4 exact
    float4 f = ((const float4*)X)[idx];
    ushort4 o;
    o.x = f2bf(f.x); o.y = f2bf(f.y); o.z = f2bf(f.z); o.w = f2bf(f.w);
    ((ushort4*)Xb)[idx] = o;
}

// ---------------------------------------------------------------------------
// CSR build over ALL 4 relations at once (grid.y = relation)
// ---------------------------------------------------------------------------
__global__ __launch_bounds__(256) void hist_kernel(
    const int* __restrict__ arows, int* __restrict__ counts)
{
    int e = blockIdx.x * 256 + threadIdx.x;
    int rl = blockIdx.y;
    if (e < NEDGE) {
        int row = arows[(size_t)rl * NEDGE + e];
        atomicAdd(&counts[rl * N_NODES + row], 1);
    }
}

// in-place per-chunk exclusive scan (1024 elems/block)
__global__ __launch_bounds__(256) void scan1_kernel(
    int* __restrict__ counts, int* __restrict__ chunksums, int M)
{
    __shared__ int s[256];
    int chunk = blockIdx.x, t = threadIdx.x;
    int base = chunk * 1024 + t * 4;
    int v0 = (base + 0 < M) ? counts[base + 0] : 0;
    int v1 = (base + 1 < M) ? counts[base + 1] : 0;
    int v2 = (base + 2 < M) ? counts[base + 2] : 0;
    int v3 = (base + 3 < M) ? counts[base + 3] : 0;
    int p1 = v0, p2 = v0 + v1, p3 = v0 + v1 + v2, tsum = p3 + v3;
    int run = tsum;
    s[t] = run;
    __syncthreads();
    for (int off = 1; off < 256; off <<= 1) {
        int other = (t >= off) ? s[t - off] : 0;
        __syncthreads();
        run += other;
        s[t] = run;
        __syncthreads();
    }
    int excl = run - tsum;
    if (t == 255) chunksums[chunk] = run;
    if (base + 0 < M) counts[base + 0] = excl;
    if (base + 1 < M) counts[base + 1] = excl + p1;
    if (base + 2 < M) counts[base + 2] = excl + p2;
    if (base + 3 < M) counts[base + 3] = excl + p3;
}

// exclusive scan of chunk sums (<=512) in place
__global__ __launch_bounds__(512) void scan2_kernel(
    int* __restrict__ chunksums, int nchunks)
{
    __shared__ int s[512];
    int t = threadIdx.x;
    int v = (t < nchunks) ? chunksums[t] : 0;
    int run = v;
    s[t] = run;
    __syncthreads();
    for (int off = 1; off < 512; off <<= 1) {
        int other = (t >= off) ? s[t - off] : 0;
        __syncthreads();
        run += other;
        s[t] = run;
        __syncthreads();
    }
    if (t < nchunks) chunksums[t] = run - v;
}

// bucket edges by (relation,row); edge word = col<<15 | bf15(val).
// counts (within-chunk excl starts) mutate into within-chunk ENDs;
// global position = bump + chunks[g>>10].
__global__ __launch_bounds__(256) void reorder_kernel(
    const int* __restrict__ arows, const int* __restrict__ acols,
    const float* __restrict__ avals,
    int* __restrict__ counts, const int* __restrict__ chunks,
    unsigned int* __restrict__ edges)
{
    int e = blockIdx.x * 256 + threadIdx.x;
    int rl = blockIdx.y;
    if (e < NEDGE) {
        size_t off = (size_t)rl * NEDGE + e;
        int row = arows[off];
        int g = rl * N_NODES + row;
        int pos = atomicAdd(&counts[g], 1) + chunks[g >> 10];
        unsigned int vb = __float_as_uint(avals[off]);
        vb += 0x7FFFu + ((vb >> 16) & 1u);         // RN-even to bf16
        edges[pos] = ((unsigned int)acols[off] << 15) | ((vb >> 16) & 0x7FFFu);
    }
}

// ---------------------------------------------------------------------------
// Mega kernel: per 32-row tile, loop over ALL 4 relations:
//   node-parallel gather (8 groups x 32 lanes, 4 nodes/group, unroll-4:
//   4 independent X-row loads in flight per group, NO atomics) ->
//   GEMM1(relu) -> GEMM2, comb accumulated in registers across relations ->
//   gate GEMM + residual + LayerNorm epilogue. One 16KB LDS tile reused.
// GEMM mapping: wave w owns rows [8w,8w+8); lane l owns cols l, l+64.
// ---------------------------------------------------------------------------
__global__ __launch_bounds__(256) void mega_kernel(
    const unsigned short* __restrict__ Xb,
    const float* __restrict__ X,
    const int* __restrict__ counts,     // within-chunk end offsets
    const int* __restrict__ chunks,     // chunk base offsets
    const unsigned int* __restrict__ edges,
    const float* __restrict__ W1,
    const float* __restrict__ bfr,
    const float* __restrict__ Wr,
    const float* __restrict__ br,
    const float* __restrict__ wsm,
    const float* __restrict__ Wg,
    const float* __restrict__ bg,
    const float* __restrict__ gamma,
    const float* __restrict__ beta,
    float* __restrict__ out)
{
    __shared__ float sIn[32][DIM];
    __shared__ float red[32][8], red2[32][8];
    __shared__ float smu[32], srs[32];

    int t = threadIdx.x;
    int row0 = blockIdx.x * 32;
    int w = t >> 6;                    // wave 0..3
    int l = t & 63;
    int grp = t >> 5, lane = t & 31;   // gather: 8 groups x 32 lanes

    float comb_acc[8][2];
#pragma unroll
    for (int rr = 0; rr < 8; ++rr) { comb_acc[rr][0] = 0.f; comb_acc[rr][1] = 0.f; }

    for (int rl = 0; rl < NREL; ++rl) {
        __syncthreads();   // sIn free (prev GEMM2 reads done / init)

        // ---- Phase A: gather, 4 X-rows in flight per group
#pragma unroll
        for (int i = 0; i < 4; ++i) {
            int ln = grp * 4 + i;
            int g = rl * N_NODES + row0 + ln;
            int s = (g == 0) ? 0 : counts[g - 1] + chunks[(g - 1) >> 10];
            int e = counts[g] + chunks[g >> 10];
            float4 a0 = make_float4(0.f, 0.f, 0.f, 0.f);
            float4 a1 = make_float4(0.f, 0.f, 0.f, 0.f);
            float4 a2 = make_float4(0.f, 0.f, 0.f, 0.f);
            float4 a3 = make_float4(0.f, 0.f, 0.f, 0.f);
            int ee = s;
            for (; ee + 4 <= e; ee += 4) {
                unsigned int p0 = edges[ee + 0];
                unsigned int p1 = edges[ee + 1];
                unsigned int p2 = edges[ee + 2];
                unsigned int p3 = edges[ee + 3];
                const ushort4* x0 = (const ushort4*)(Xb + ((size_t)(p0 >> 15) << 7));
                const ushort4* x1 = (const ushort4*)(Xb + ((size_t)(p1 >> 15) << 7));
                const ushort4* x2 = (const ushort4*)(Xb + ((size_t)(p2 >> 15) << 7));
                const ushort4* x3 = (const ushort4*)(Xb + ((size_t)(p3 >> 15) << 7));
                ushort4 q0 = x0[lane];
                ushort4 q1 = x1[lane];
                ushort4 q2 = x2[lane];
                ushort4 q3 = x3[lane];
                float v0 = __uint_as_float((p0 & 0x7FFFu) << 16);
                float v1 = __uint_as_float((p1 & 0x7FFFu) << 16);
                float v2 = __uint_as_float((p2 & 0x7FFFu) << 16);
                float v3 = __uint_as_float((p3 & 0x7FFFu) << 16);
                a0.x += v0 * bf2f(q0.x); a0.y += v0 * bf2f(q0.y);
                a0.z += v0 * bf2f(q0.z); a0.w += v0 * bf2f(q0.w);
                a1.x += v1 * bf2f(q1.x); a1.y += v1 * bf2f(q1.y);
                a1.z += v1 * bf2f(q1.z); a1.w += v1 * bf2f(q1.w);
                a2.x += v2 * bf2f(q2.x); a2.y += v2 * bf2f(q2.y);
                a2.z += v2 * bf2f(q2.z); a2.w += v2 * bf2f(q2.w);
                a3.x += v3 * bf2f(q3.x); a3.y += v3 * bf2f(q3.y);
                a3.z += v3 * bf2f(q3.z); a3.w += v3 * bf2f(q3.w);
            }
            for (; ee < e; ++ee) {
                unsigned int p0 = edges[ee];
                const ushort4* x0 = (const ushort4*)(Xb + ((size_t)(p0 >> 15) << 7));
                ushort4 q0 = x0[lane];
                float v0 = __uint_as_float((p0 & 0x7FFFu) << 16);
                a0.x += v0 * bf2f(q0.x); a0.y += v0 * bf2f(q0.y);
                a0.z += v0 * bf2f(q0.z); a0.w += v0 * bf2f(q0.w);
            }
            a0.x += a1.x + a2.x + a3.x;
            a0.y += a1.y + a2.y + a3.y;
            a0.z += a1.z + a2.z + a3.z;
            a0.w += a1.w + a2.w + a3.w;
            ((float4*)&sIn[ln][0])[lane] = a0;
        }
        __syncthreads();

        // ---- Phase B: GEMM1 (msg @ W1), relu + bfr, back into sIn
        float acc1[8][2];
#pragma unroll
        for (int rr = 0; rr < 8; ++rr) { acc1[rr][0] = 0.f; acc1[rr][1] = 0.f; }
        for (int k4 = 0; k4 < DIM / 4; ++k4) {
            float wa[4], wb4[4];
#pragma unroll
            for (int j = 0; j < 4; ++j) {
                wa[j]  = W1[(k4 * 4 + j) * DIM + l];
                wb4[j] = W1[(k4 * 4 + j) * DIM + l + 64];
            }
#pragma unroll
            for (int rr = 0; rr < 8; ++rr) {
                float4 m = *(const float4*)&sIn[w * 8 + rr][k4 * 4];
                acc1[rr][0] += m.x * wa[0]  + m.y * wa[1]  + m.z * wa[2]  + m.w * wa[3];
                acc1[rr][1] += m.x * wb4[0] + m.y * wb4[1] + m.z * wb4[2] + m.w * wb4[3];
            }
        }
        __syncthreads();
        {
            float b0 = bfr[rl * DIM + l], b1 = bfr[rl * DIM + l + 64];
#pragma unroll
            for (int rr = 0; rr < 8; ++rr) {
                sIn[w * 8 + rr][l]      = fmaxf(acc1[rr][0] + b0, 0.f);
                sIn[w * 8 + rr][l + 64] = fmaxf(acc1[rr][1] + b1, 0.f);
            }
        }
        __syncthreads();

        // ---- Phase C: GEMM2 (@ W_rel[rl]), weighted accumulate in regs
        const float* W2 = Wr + (size_t)rl * DIM * DIM;
        float acc2[8][2];
#pragma unroll
        for (int rr = 0; rr < 8; ++rr) { acc2[rr][0] = 0.f; acc2[rr][1] = 0.f; }
        for (int k4 = 0; k4 < DIM / 4; ++k4) {
            float wa[4], wb4[4];
#pragma unroll
            for (int j = 0; j < 4; ++j) {
                wa[j]  = W2[(k4 * 4 + j) * DIM + l];
                wb4[j] = W2[(k4 * 4 + j) * DIM + l + 64];
            }
#pragma unroll
            for (int rr = 0; rr < 8; ++rr) {
                float4 m = *(const float4*)&sIn[w * 8 + rr][k4 * 4];
                acc2[rr][0] += m.x * wa[0]  + m.y * wa[1]  + m.z * wa[2]  + m.w * wa[3];
                acc2[rr][1] += m.x * wb4[0] + m.y * wb4[1] + m.z * wb4[2] + m.w * wb4[3];
            }
        }
        {
            float wr_ = wsm[rl];
            float bb0 = br[rl * DIM + l], bb1 = br[rl * DIM + l + 64];
#pragma unroll
            for (int rr = 0; rr < 8; ++rr) {
                comb_acc[rr][0] += wr_ * (acc2[rr][0] + bb0);
                comb_acc[rr][1] += wr_ * (acc2[rr][1] + bb1);
            }
        }
    }

    // ---- Final: out = LN(X + sigmoid(X@Wg + bg) * comb)
    __syncthreads();
    {
        const float4* src = (const float4*)(X + (size_t)row0 * DIM);
        float4* dst = (float4*)&sIn[0][0];
        for (int i = t; i < 32 * DIM / 4; i += 256) dst[i] = src[i];
    }
    __syncthreads();

    float accg[8][2];
#pragma unroll
    for (int rr = 0; rr < 8; ++rr) { accg[rr][0] = 0.f; accg[rr][1] = 0.f; }
    for (int k4 = 0; k4 < DIM / 4; ++k4) {
        float wa[4], wb4[4];
#pragma unroll
        for (int j = 0; j < 4; ++j) {
            wa[j]  = Wg[(k4 * 4 + j) * DIM + l];
            wb4[j] = Wg[(k4 * 4 + j) * DIM + l + 64];
        }
#pragma unroll
        for (int rr = 0; rr < 8; ++rr) {
            float4 m = *(const float4*)&sIn[w * 8 + rr][k4 * 4];
            accg[rr][0] += m.x * wa[0]  + m.y * wa[1]  + m.z * wa[2]  + m.w * wa[3];
            accg[rr][1] += m.x * wb4[0] + m.y * wb4[1] + m.z * wb4[2] + m.w * wb4[3];
        }
    }
    float xv[8][2];
    {
        float bg0 = bg[l], bg1 = bg[l + 64];
#pragma unroll
        for (int rr = 0; rr < 8; ++rr) {
            int row = w * 8 + rr;
            float g0 = 1.f / (1.f + expf(-(accg[rr][0] + bg0)));
            float g1 = 1.f / (1.f + expf(-(accg[rr][1] + bg1)));
            xv[rr][0] = sIn[row][l]      + g0 * comb_acc[rr][0];
            xv[rr][1] = sIn[row][l + 64] + g1 * comb_acc[rr][1];
        }
    }
    __syncthreads();
#pragma unroll
    for (int rr = 0; rr < 8; ++rr) {
        sIn[w * 8 + rr][l]      = xv[rr][0];
        sIn[w * 8 + rr][l + 64] = xv[rr][1];
    }
    __syncthreads();

    {
        int row = t >> 3, seg = t & 7;
        float s = 0.f, s2 = 0.f;
#pragma unroll
        for (int i = 0; i < 16; ++i) {
            float v = sIn[row][seg * 16 + i];
            s += v; s2 += v * v;
        }
        red[row][seg] = s;
        red2[row][seg] = s2;
    }
    __syncthreads();
    if ((t & 7) == 0) {
        int row = t >> 3;
        float ts = 0.f, ts2 = 0.f;
#pragma unroll
        for (int i = 0; i < 8; ++i) { ts += red[row][i]; ts2 += red2[row][i]; }
        float mu = ts / DIM;
        float var = ts2 / DIM - mu * mu;
        smu[row] = mu;
        srs[row] = rsqrtf(var + LN_EPS);
    }
    __syncthreads();
    {
        float gm0 = gamma[l], gm1 = gamma[l + 64];
        float bt0 = beta[l],  bt1 = beta[l + 64];
#pragma unroll
        for (int rr = 0; rr < 8; ++rr) {
            int row = w * 8 + rr;
            size_t gi = (size_t)(row0 + row) * DIM + l;
            out[gi]      = (sIn[row][l]      - smu[row]) * srs[row] * gm0 + bt0;
            out[gi + 64] = (sIn[row][l + 64] - smu[row]) * srs[row] * gm1 + bt1;
        }
    }
}

// ---------------------------------------------------------------------------
extern "C" void kernel_launch(void* const* d_in, const int* in_sizes, int n_in,
                              void* d_out, int out_size, void* d_ws, size_t ws_size,
                              hipStream_t stream) {
    const float* X     = (const float*)d_in[0];
    const float* rel   = (const float*)d_in[1];
    const int*   arows = (const int*)d_in[2];
    const int*   acols = (const int*)d_in[3];
    const float* avals = (const float*)d_in[4];
    const float* Wf    = (const float*)d_in[5];
    const float* bf    = (const float*)d_in[6];
    const float* Wr    = (const float*)d_in[7];
    const float* br    = (const float*)d_in[8];
    const float* rw    = (const float*)d_in[9];
    const float* Wg    = (const float*)d_in[10];
    const float* bg    = (const float*)d_in[11];
    const float* gamma = (const float*)d_in[12];
    const float* beta  = (const float*)d_in[13];
    float* out = (float*)d_out;

    // workspace: Xb 25.6MB + edges 4*E*4B = 25.6MB + counts 1.6MB + small
    //          ~= 52.81 MB  (nr=4 budget proven available in rounds 2-3)
    const size_t XB_B = (size_t)N_NODES * DIM * 2;
    unsigned short* Xb     = (unsigned short*)d_ws;
    unsigned int*   edges  = (unsigned int*)((char*)d_ws + XB_B);
    int*            counts = (int*)(edges + (size_t)NREL * NEDGE);
    int*            chunks = counts + NREL * N_NODES;
    float*          bfr    = (float*)(chunks + 512);
    float*          wsm    = bfr + NREL * DIM;

    prep_kernel<<<1, 512, 0, stream>>>(rel, Wf, bf, rw, bfr, wsm);
    xb_kernel<<<N_NODES * DIM / 4 / 256, 256, 0, stream>>>(X, Xb);

    const int EB = (NEDGE + 255) / 256;        // 6250
    const int M = NREL * N_NODES;              // 400000
    const int nch = (M + 1023) / 1024;         // 391
    hipMemsetAsync(counts, 0, (size_t)M * sizeof(int), stream);
    hist_kernel<<<dim3(EB, NREL), 256, 0, stream>>>(arows, counts);
    scan1_kernel<<<nch, 256, 0, stream>>>(counts, chunks, M);
    scan2_kernel<<<1, 512, 0, stream>>>(chunks, nch);
    reorder_kernel<<<dim3(EB, NREL), 256, 0, stream>>>(
        arows, acols, avals, counts, chunks, edges);
    mega_kernel<<<N_NODES / 32, 256, 0, stream>>>(
        Xb, X, counts, chunks, edges, Wf, bfr, Wr, br, wsm,
        Wg, bg, gamma, beta, out);
}